// Round 1
// baseline (427.845 us; speedup 1.0000x reference)
//
#include <hip/hip_runtime.h>
#include <hip/hip_bf16.h>

#define BATCH 8
#define DIM   512
#define TLEN  4096
#define INTER 1536
#define NTOK  (BATCH*TLEN)

typedef __attribute__((ext_vector_type(4))) float f32x4;
typedef __attribute__((ext_vector_type(8))) short s16x8;

__device__ __forceinline__ float bf2f(short s) {
  unsigned u = ((unsigned)(unsigned short)s) << 16;
  return __uint_as_float(u);
}
__device__ __forceinline__ short f2bf(float f) {
  union { __hip_bfloat16 h; unsigned short u; } cv;
  cv.h = __float2bfloat16(f);
  return (short)cv.u;
}
__device__ __forceinline__ void async16(void* lds, const void* g) {
  __builtin_amdgcn_global_load_lds((const __attribute__((address_space(1))) void*)g,
                                   (__attribute__((address_space(3))) void*)lds, 16, 0, 0);
}

// ---------------- weight-scale reduction (two-stage, deterministic) ----------
__global__ __launch_bounds__(256)
void reduce_abs_k(const float* __restrict__ w, int n, float* __restrict__ partial) {
  int tid = threadIdx.x;
  float s = 0.f;
  for (int i = blockIdx.x * 256 + tid; i < n; i += gridDim.x * 256) s += fabsf(w[i]);
  #pragma unroll
  for (int off = 32; off; off >>= 1) s += __shfl_xor(s, off);
  __shared__ float ls[4];
  if ((tid & 63) == 0) ls[tid >> 6] = s;
  __syncthreads();
  if (tid == 0) partial[blockIdx.x] = ls[0] + ls[1] + ls[2] + ls[3];
}

__global__ void finalize_scales_k(float* __restrict__ ws) {
  // partials: w1 at [16..143], w2 at [144..271], dw at [272..279]
  if (threadIdx.x == 0) {
    float s = 0.f;
    for (int i = 0; i < 128; ++i) s += ws[16 + i];
    ws[0] = fmaxf(s / 786432.f, 1e-5f);
    s = 0.f;
    for (int i = 0; i < 128; ++i) s += ws[144 + i];
    ws[1] = fmaxf(s / 786432.f, 1e-5f);
    s = 0.f;
    for (int i = 0; i < 8; ++i) s += ws[272 + i];
    ws[2] = fmaxf(s / 3584.f, 1e-5f);
  }
}

__global__ __launch_bounds__(256)
void quant_w_k(const float* __restrict__ w, int n, const float* __restrict__ sp,
               short* __restrict__ o) {
  int i = blockIdx.x * 256 + threadIdx.x;
  if (i < n) {
    float s = sp[0];
    float q = fminf(fmaxf(rintf(w[i] / s), -1.f), 1.f) * s;
    o[i] = f2bf(q);
  }
}

// ---------------- per-token absmax of x over DIM ----------------------------
__global__ __launch_bounds__(256)
void amax_k(const float* __restrict__ x, float* __restrict__ amax) {
  int tid = threadIdx.x;
  int b = blockIdx.y;
  int t0 = blockIdx.x * 128;
  int tk = tid & 127, half = tid >> 7;
  const float* xb = x + ((size_t)b * DIM + half * 256) * TLEN + t0 + tk;
  float m = 0.f;
  for (int c = 0; c < 256; ++c) m = fmaxf(m, fabsf(xb[(size_t)c * TLEN]));
  __shared__ float pm[256];
  pm[tid] = m;
  __syncthreads();
  if (tid < 128) amax[(size_t)b * TLEN + t0 + tid] = fmaxf(pm[tid], pm[tid + 128]);
}

// ---------------- fused: act-quant -> depthwise conv -> LN -> act-quant -----
__global__ __launch_bounds__(256)
void conv_ln_quant_k(const float* __restrict__ x, const float* __restrict__ dww,
                     const float* __restrict__ dwb, const float* __restrict__ lng,
                     const float* __restrict__ lnb, const float* __restrict__ amax,
                     const float* __restrict__ scales, short* __restrict__ yq) {
  __shared__ float ly[16 * 517];      // [token][channel], stride 517 to dodge banks
  __shared__ float lg[DIM], lb[DIM];
  __shared__ float sx[22], sxi[22];
  const int tid = threadIdx.x;
  const int b = blockIdx.y;
  const int t0 = blockIdx.x * 16;

  lg[tid] = lng[tid]; lg[tid + 256] = lng[tid + 256];
  lb[tid] = lnb[tid]; lb[tid + 256] = lnb[tid + 256];
  if (tid < 22) {
    int tg = t0 - 3 + tid;
    float a = (tg >= 0 && tg < TLEN) ? amax[(size_t)b * TLEN + tg] : 1.f;
    float m = fmaxf(a, 1e-5f);
    sx[tid] = 127.f / m;
    sxi[tid] = m * (1.f / 127.f);
  }
  __syncthreads();

  const float sdw = scales[2];
  const float rs = 1.0f / sdw;
  const int tx = tid & 15, cg = tid >> 4;
  for (int ci = 0; ci < 32; ++ci) {
    int c = ci * 16 + cg;
    const float* xr = x + ((size_t)b * DIM + c) * TLEN;
    float acc = dwb[c];
    #pragma unroll
    for (int k = 0; k < 7; ++k) {
      float wq = fminf(fmaxf(rintf(dww[c * 7 + k] * rs), -1.f), 1.f) * sdw;
      int tg = t0 + tx + k - 3;
      if (tg >= 0 && tg < TLEN) {
        int j = tx + k;
        float q = fminf(fmaxf(rintf(xr[tg] * sx[j]), -128.f), 127.f) * sxi[j];
        acc += wq * q;
      }
    }
    ly[tx * 517 + c] = acc;
  }
  __syncthreads();

  const int lane = tid & 63, w = tid >> 6;
  for (int tw = 0; tw < 4; ++tw) {
    int t = w * 4 + tw;
    float v[8];
    float s = 0.f, sq = 0.f;
    #pragma unroll
    for (int j = 0; j < 8; ++j) {
      float vv = ly[t * 517 + lane + 64 * j];
      v[j] = vv; s += vv; sq += vv * vv;
    }
    #pragma unroll
    for (int off = 32; off; off >>= 1) { s += __shfl_xor(s, off); sq += __shfl_xor(sq, off); }
    float mu = s * (1.f / 512.f);
    float var = sq * (1.f / 512.f) - mu * mu;
    float rstd = rsqrtf(var + 1e-6f);
    float amx = 0.f;
    #pragma unroll
    for (int j = 0; j < 8; ++j) {
      int c = lane + 64 * j;
      float nv = (v[j] - mu) * rstd * lg[c] + lb[c];
      v[j] = nv;
      amx = fmaxf(amx, fabsf(nv));
    }
    #pragma unroll
    for (int off = 32; off; off >>= 1) amx = fmaxf(amx, __shfl_xor(amx, off));
    float m = fmaxf(amx, 1e-5f);
    float ss = 127.f / m, si = m * (1.f / 127.f);
    size_t base = ((size_t)(b * TLEN + t0 + t)) * DIM;
    #pragma unroll
    for (int j = 0; j < 8; ++j) {
      int c = lane + 64 * j;
      float q = fminf(fmaxf(rintf(v[j] * ss), -128.f), 127.f) * si;
      yq[base + c] = f2bf(q);
    }
  }
}

// ---------------- GEMM1: h[t][f] = gelu(yq[t][:]·wq1[f][:] + b1[f]) ---------
__global__ __launch_bounds__(256)
void gemm1_k(const short* __restrict__ Aq, const short* __restrict__ Bq,
             const float* __restrict__ bias, short* __restrict__ h) {
  constexpr int KD = DIM;
  __shared__ short lA[128 * 32];
  __shared__ short lB[128 * 32];
  const int tid = threadIdx.x;
  const int n0 = blockIdx.x * 128, m0 = blockIdx.y * 128;
  const short* gA = Aq + (size_t)(m0 + (tid >> 2)) * KD + (tid & 3) * 8;
  const short* gB = Bq + (size_t)(n0 + (tid >> 2)) * KD + (tid & 3) * 8;
  char* la = (char*)lA + tid * 16;
  char* lbp = (char*)lB + tid * 16;
  f32x4 acc[4][4] = {};
  const int lane = tid & 63, wid = tid >> 6;
  const int wm = (wid >> 1) * 64, wn = (wid & 1) * 64;
  const int lr = lane & 15, kb = (lane >> 4) * 8;
  for (int kt = 0; kt < KD / 32; ++kt) {
    async16(la, gA + kt * 32);
    async16(la + 4096, gA + 64 * KD + kt * 32);
    async16(lbp, gB + kt * 32);
    async16(lbp + 4096, gB + 64 * KD + kt * 32);
    __syncthreads();
    s16x8 af[4], bfr[4];
    #pragma unroll
    for (int i = 0; i < 4; ++i) af[i] = *(const s16x8*)(lA + (wm + i * 16 + lr) * 32 + kb);
    #pragma unroll
    for (int i = 0; i < 4; ++i) bfr[i] = *(const s16x8*)(lB + (wn + i * 16 + lr) * 32 + kb);
    #pragma unroll
    for (int i = 0; i < 4; ++i)
      #pragma unroll
      for (int j = 0; j < 4; ++j)
        acc[i][j] = __builtin_amdgcn_mfma_f32_16x16x32_bf16(af[i], bfr[j], acc[i][j], 0, 0, 0);
    __syncthreads();
  }
  #pragma unroll
  for (int i = 0; i < 4; ++i) {
    const int tok0 = m0 + wm + i * 16 + ((lane >> 4) << 2);
    #pragma unroll
    for (int j = 0; j < 4; ++j) {
      const int f = n0 + wn + j * 16 + lr;
      const float bb = bias[f];
      #pragma unroll
      for (int r = 0; r < 4; ++r) {
        float hv = acc[i][j][r] + bb;
        hv = 0.5f * hv * (1.0f + erff(hv * 0.70710678118654752f));
        h[(size_t)(tok0 + r) * INTER + f] = f2bf(hv);
      }
    }
  }
}

// ---------------- per-row act-quant of h (in place) -------------------------
__global__ __launch_bounds__(192)
void rowquant_k(short* __restrict__ h) {
  __shared__ float wmx[3];
  const int row = blockIdx.x, tid = threadIdx.x;
  short* hr = h + (size_t)row * INTER;
  s16x8 v = *(const s16x8*)(hr + tid * 8);
  float f[8];
  float m = 0.f;
  #pragma unroll
  for (int j = 0; j < 8; ++j) { f[j] = bf2f(v[j]); m = fmaxf(m, fabsf(f[j])); }
  #pragma unroll
  for (int off = 32; off; off >>= 1) m = fmaxf(m, __shfl_xor(m, off));
  if ((tid & 63) == 0) wmx[tid >> 6] = m;
  __syncthreads();
  m = fmaxf(fmaxf(wmx[0], wmx[1]), wmx[2]);
  float mm = fmaxf(m, 1e-5f);
  float ss = 127.f / mm, si = mm * (1.f / 127.f);
  s16x8 o;
  #pragma unroll
  for (int j = 0; j < 8; ++j) {
    float q = fminf(fmaxf(rintf(f[j] * ss), -128.f), 127.f) * si;
    o[j] = f2bf(q);
  }
  *(s16x8*)(hr + tid * 8) = o;
}

// ---------------- GEMM2: out[b,c,t] = x + gamma[c]*(hq[t][:]·wq2[c][:]+b2) --
__global__ __launch_bounds__(256)
void gemm2_k(const short* __restrict__ Aq /*wq2*/, const short* __restrict__ Bq /*hq*/,
             const float* __restrict__ b2, const float* __restrict__ gamma,
             const float* __restrict__ x, float* __restrict__ out) {
  constexpr int KD = INTER;
  __shared__ short lA[128 * 32];
  __shared__ short lB[128 * 32];
  const int tid = threadIdx.x;
  const int m0 = blockIdx.x * 128;   // channel tiles (4)
  const int n0 = blockIdx.y * 128;   // token tiles (256)
  const short* gA = Aq + (size_t)(m0 + (tid >> 2)) * KD + (tid & 3) * 8;
  const short* gB = Bq + (size_t)(n0 + (tid >> 2)) * KD + (tid & 3) * 8;
  char* la = (char*)lA + tid * 16;
  char* lbp = (char*)lB + tid * 16;
  f32x4 acc[4][4] = {};
  const int lane = tid & 63, wid = tid >> 6;
  const int wm = (wid >> 1) * 64, wn = (wid & 1) * 64;
  const int lr = lane & 15, kb = (lane >> 4) * 8;
  for (int kt = 0; kt < KD / 32; ++kt) {
    async16(la, gA + kt * 32);
    async16(la + 4096, gA + 64 * KD + kt * 32);
    async16(lbp, gB + kt * 32);
    async16(lbp + 4096, gB + 64 * KD + kt * 32);
    __syncthreads();
    s16x8 af[4], bfr[4];
    #pragma unroll
    for (int i = 0; i < 4; ++i) af[i] = *(const s16x8*)(lA + (wm + i * 16 + lr) * 32 + kb);
    #pragma unroll
    for (int i = 0; i < 4; ++i) bfr[i] = *(const s16x8*)(lB + (wn + i * 16 + lr) * 32 + kb);
    #pragma unroll
    for (int i = 0; i < 4; ++i)
      #pragma unroll
      for (int j = 0; j < 4; ++j)
        acc[i][j] = __builtin_amdgcn_mfma_f32_16x16x32_bf16(af[i], bfr[j], acc[i][j], 0, 0, 0);
    __syncthreads();
  }
  #pragma unroll
  for (int i = 0; i < 4; ++i) {
    const int c0 = m0 + wm + i * 16 + ((lane >> 4) << 2);
    #pragma unroll
    for (int j = 0; j < 4; ++j) {
      const int tok = n0 + wn + j * 16 + lr;
      const int bb = tok >> 12;
      const int tt = tok & 4095;
      #pragma unroll
      for (int r = 0; r < 4; ++r) {
        const int c = c0 + r;
        float o = acc[i][j][r] + b2[c];
        size_t idx = ((size_t)(bb * DIM + c)) * TLEN + tt;
        out[idx] = x[idx] + gamma[c] * o;
      }
    }
  }
}

// ---------------------------------------------------------------------------
extern "C" void kernel_launch(void* const* d_in, const int* in_sizes, int n_in,
                              void* d_out, int out_size, void* d_ws, size_t ws_size,
                              hipStream_t stream) {
  const float* x    = (const float*)d_in[0];
  const float* dww  = (const float*)d_in[1];
  const float* dwb  = (const float*)d_in[2];
  const float* lng  = (const float*)d_in[3];
  const float* lnb  = (const float*)d_in[4];
  const float* w1   = (const float*)d_in[5];
  const float* b1   = (const float*)d_in[6];
  const float* w2   = (const float*)d_in[7];
  const float* b2   = (const float*)d_in[8];
  const float* gam  = (const float*)d_in[9];
  float* out = (float*)d_out;

  // ws layout (bytes):
  //   0        : scales + partials (4 KB)
  //   4096     : amax  [NTOK] f32            (131072 B)
  //   135168   : wq1   [INTER*DIM] bf16      (1572864 B)
  //   1708032  : wq2   [DIM*INTER] bf16      (1572864 B)
  //   3280896  : yq    [NTOK*DIM]  bf16      (33554432 B)
  //   36835328 : h     [NTOK*INTER] bf16     (100663296 B)  -> total 137498624
  const size_t NEEDED = 137498624;
  if (ws_size < NEEDED) return;  // leave output poisoned -> clean failure signal

  char* ws = (char*)d_ws;
  float* scales = (float*)ws;
  float* amax   = (float*)(ws + 4096);
  short* wq1    = (short*)(ws + 135168);
  short* wq2    = (short*)(ws + 1708032);
  short* yq     = (short*)(ws + 3280896);
  short* h      = (short*)(ws + 36835328);

  reduce_abs_k<<<128, 256, 0, stream>>>(w1, INTER * DIM, scales + 16);
  reduce_abs_k<<<128, 256, 0, stream>>>(w2, INTER * DIM, scales + 144);
  reduce_abs_k<<<8, 256, 0, stream>>>(dww, DIM * 7, scales + 272);
  finalize_scales_k<<<1, 64, 0, stream>>>(scales);
  quant_w_k<<<3072, 256, 0, stream>>>(w1, INTER * DIM, scales + 0, wq1);
  quant_w_k<<<3072, 256, 0, stream>>>(w2, INTER * DIM, scales + 1, wq2);
  amax_k<<<dim3(TLEN / 128, BATCH), 256, 0, stream>>>(x, amax);
  conv_ln_quant_k<<<dim3(TLEN / 16, BATCH), 256, 0, stream>>>(x, dww, dwb, lng, lnb,
                                                              amax, scales, yq);
  gemm1_k<<<dim3(INTER / 128, NTOK / 128), 256, 0, stream>>>(yq, wq1, b1, h);
  rowquant_k<<<NTOK, 192, 0, stream>>>(h);
  gemm2_k<<<dim3(DIM / 128, NTOK / 128), 256, 0, stream>>>(wq2, h, b2, gam, x, out);
}

// Round 2
// 365.197 us; speedup vs baseline: 1.1715x; 1.1715x over previous
//
#include <hip/hip_runtime.h>
#include <hip/hip_bf16.h>

#define BATCH 8
#define DIM   512
#define TLEN  4096
#define INTER 1536
#define NTOK  (BATCH*TLEN)

typedef __attribute__((ext_vector_type(4))) float f32x4;
typedef __attribute__((ext_vector_type(8))) short s16x8;

__device__ __forceinline__ float bf2f(short s) {
  unsigned u = ((unsigned)(unsigned short)s) << 16;
  return __uint_as_float(u);
}
__device__ __forceinline__ short f2bf(float f) {
  union { __hip_bfloat16 h; unsigned short u; } cv;
  cv.h = __float2bfloat16(f);
  return (short)cv.u;
}
__device__ __forceinline__ void async16(void* lds, const void* g) {
  __builtin_amdgcn_global_load_lds((const __attribute__((address_space(1))) void*)g,
                                   (__attribute__((address_space(3))) void*)lds, 16, 0, 0);
}

// ---------------- weight-scale reduction (two-stage, deterministic) ----------
__global__ __launch_bounds__(256)
void reduce_abs_k(const float* __restrict__ w, int n, float* __restrict__ partial) {
  int tid = threadIdx.x;
  float s = 0.f;
  for (int i = blockIdx.x * 256 + tid; i < n; i += gridDim.x * 256) s += fabsf(w[i]);
  #pragma unroll
  for (int off = 32; off; off >>= 1) s += __shfl_xor(s, off);
  __shared__ float ls[4];
  if ((tid & 63) == 0) ls[tid >> 6] = s;
  __syncthreads();
  if (tid == 0) partial[blockIdx.x] = ls[0] + ls[1] + ls[2] + ls[3];
}

__global__ void finalize_scales_k(float* __restrict__ ws) {
  // partials: w1 at [16..143], w2 at [144..271], dw at [272..279]
  if (threadIdx.x == 0) {
    float s = 0.f;
    for (int i = 0; i < 128; ++i) s += ws[16 + i];
    ws[0] = fmaxf(s / 786432.f, 1e-5f);
    s = 0.f;
    for (int i = 0; i < 128; ++i) s += ws[144 + i];
    ws[1] = fmaxf(s / 786432.f, 1e-5f);
    s = 0.f;
    for (int i = 0; i < 8; ++i) s += ws[272 + i];
    ws[2] = fmaxf(s / 3584.f, 1e-5f);
  }
}

__global__ __launch_bounds__(256)
void quant_w_k(const float* __restrict__ w, int n, const float* __restrict__ sp,
               short* __restrict__ o) {
  int i = blockIdx.x * 256 + threadIdx.x;
  if (i < n) {
    float s = sp[0];
    float q = fminf(fmaxf(rintf(w[i] / s), -1.f), 1.f) * s;
    o[i] = f2bf(q);
  }
}

// ---------------- per-token absmax of x over DIM ----------------------------
__global__ __launch_bounds__(256)
void amax_k(const float* __restrict__ x, float* __restrict__ amax) {
  int tid = threadIdx.x;
  int b = blockIdx.y;
  int t0 = blockIdx.x * 128;
  int tk = tid & 127, half = tid >> 7;
  const float* xb = x + ((size_t)b * DIM + half * 256) * TLEN + t0 + tk;
  float m = 0.f;
  for (int c = 0; c < 256; ++c) m = fmaxf(m, fabsf(xb[(size_t)c * TLEN]));
  __shared__ float pm[256];
  pm[tid] = m;
  __syncthreads();
  if (tid < 128) amax[(size_t)b * TLEN + t0 + tid] = fmaxf(pm[tid], pm[tid + 128]);
}

// ---------------- fused: act-quant -> depthwise conv -> LN -> act-quant -----
// 64-token tile, thread = channel pair, float4 sliding-window conv,
// wave-parallel LN from bf16 LDS tile.
__global__ __launch_bounds__(256)
void conv_ln_quant_k(const float* __restrict__ x, const float* __restrict__ dww,
                     const float* __restrict__ dwb, const float* __restrict__ lng,
                     const float* __restrict__ lnb, const float* __restrict__ amax,
                     const float* __restrict__ scales, short* __restrict__ yq) {
  __shared__ short ly[64 * 512];          // [t][c] bf16, row = 1024 B
  __shared__ float sx[72], sxi[72];
  const int tid = threadIdx.x;
  const int b = blockIdx.y;
  const int t0 = blockIdx.x * 64;

  if (tid < 72) {
    int tg = t0 - 4 + tid;
    float a = (tg >= 0 && tg < TLEN) ? amax[(size_t)b * TLEN + tg] : 1.f;
    float m = fmaxf(a, 1e-5f);
    sx[tid] = 127.f / m;
    sxi[tid] = m * (1.f / 127.f);
  }
  __syncthreads();

  const float sdw = scales[2];
  const float rs = 1.f / sdw;
  const int c0 = tid * 2;
  float w0[7], w1[7];
  #pragma unroll
  for (int k = 0; k < 7; ++k) {
    w0[k] = fminf(fmaxf(rintf(dww[c0 * 7 + k] * rs), -1.f), 1.f) * sdw;
    w1[k] = fminf(fmaxf(rintf(dww[c0 * 7 + 7 + k] * rs), -1.f), 1.f) * sdw;
  }
  const float bias0 = dwb[c0], bias1 = dwb[c0 + 1];
  const float* xr0 = x + ((size_t)b * DIM + c0) * TLEN + t0;
  const float* xr1 = xr0 + TLEN;
  const bool interior = (t0 >= 4) && (t0 + 68 <= TLEN);

  // load 4 floats at chunk u (covers global t = t0-4+4u .. +3), quantize once
  #define LOADQ(xr, u, Q) do {                                            \
    f32x4 L_;                                                             \
    if (interior) L_ = *(const f32x4*)((xr) - 4 + 4 * (u));               \
    else {                                                                \
      _Pragma("unroll")                                                   \
      for (int e_ = 0; e_ < 4; ++e_) {                                    \
        int tg_ = t0 - 4 + 4 * (u) + e_;                                  \
        L_[e_] = (tg_ >= 0 && tg_ < TLEN) ? (xr)[-4 + 4 * (u) + e_] : 0.f;\
      }                                                                   \
    }                                                                     \
    _Pragma("unroll")                                                     \
    for (int e_ = 0; e_ < 4; ++e_) {                                      \
      int j_ = 4 * (u) + e_;                                              \
      Q[e_] = fminf(fmaxf(rintf(L_[e_] * sx[j_]), -128.f), 127.f) * sxi[j_]; \
    }                                                                     \
  } while (0)

  f32x4 A0, A1, A2, B0, B1, B2;
  LOADQ(xr0, 0, A0); LOADQ(xr0, 1, A1);
  LOADQ(xr1, 0, B0); LOADQ(xr1, 1, B1);
  #pragma unroll 4
  for (int u = 0; u < 16; ++u) {
    LOADQ(xr0, u + 2, A2);
    LOADQ(xr1, u + 2, B2);
    // output t' = 4u+s needs quantized inputs at window index i = s+1+k
    // window: A0 = qv[4u..4u+3], A1 = qv[4u+4..4u+7], A2 = qv[4u+8..4u+11]
    #pragma unroll
    for (int s = 0; s < 4; ++s) {
      float a0 = bias0, a1 = bias1;
      #pragma unroll
      for (int k = 0; k < 7; ++k) {
        const int i = s + 1 + k;
        const float qa = (i < 4) ? A0[i & 3] : (i < 8) ? A1[i & 3] : A2[i & 3];
        const float qb = (i < 4) ? B0[i & 3] : (i < 8) ? B1[i & 3] : B2[i & 3];
        a0 += w0[k] * qa;
        a1 += w1[k] * qb;
      }
      const int t = 4 * u + s;
      unsigned pk = (unsigned)(unsigned short)f2bf(a0) |
                    ((unsigned)(unsigned short)f2bf(a1) << 16);
      *(unsigned*)((char*)ly + t * 1024 + tid * 4) = pk;
    }
    A0 = A1; A1 = A2; B0 = B1; B1 = B2;
  }
  #undef LOADQ
  __syncthreads();

  // LN + act-quant: wave w handles tokens w*16 .. w*16+15, one per iteration
  const int lane = tid & 63, w = tid >> 6;
  float gg[8], bb[8];
  #pragma unroll
  for (int j = 0; j < 8; ++j) { gg[j] = lng[lane * 8 + j]; bb[j] = lnb[lane * 8 + j]; }
  for (int i = 0; i < 16; ++i) {
    const int t = w * 16 + i;
    s16x8 v = *(const s16x8*)((char*)ly + t * 1024 + lane * 16);
    float f[8];
    float s = 0.f, sq = 0.f;
    #pragma unroll
    for (int j = 0; j < 8; ++j) { f[j] = bf2f(v[j]); s += f[j]; sq += f[j] * f[j]; }
    #pragma unroll
    for (int off = 32; off; off >>= 1) { s += __shfl_xor(s, off); sq += __shfl_xor(sq, off); }
    const float mu = s * (1.f / 512.f);
    const float var = sq * (1.f / 512.f) - mu * mu;
    const float rstd = rsqrtf(var + 1e-6f);
    float amx = 0.f;
    #pragma unroll
    for (int j = 0; j < 8; ++j) {
      f[j] = (f[j] - mu) * rstd * gg[j] + bb[j];
      amx = fmaxf(amx, fabsf(f[j]));
    }
    #pragma unroll
    for (int off = 32; off; off >>= 1) amx = fmaxf(amx, __shfl_xor(amx, off));
    const float m = fmaxf(amx, 1e-5f);
    const float ss = 127.f / m, si = m * (1.f / 127.f);
    s16x8 o;
    #pragma unroll
    for (int j = 0; j < 8; ++j) {
      float q = fminf(fmaxf(rintf(f[j] * ss), -128.f), 127.f) * si;
      o[j] = f2bf(q);
    }
    *(s16x8*)(yq + ((size_t)(b * TLEN + t0 + t)) * DIM + lane * 8) = o;
  }
}

// ---------------- GEMM1: h[t][f] = gelu(yq[t][:]·wq1[f][:] + b1[f]) ---------
__global__ __launch_bounds__(256)
void gemm1_k(const short* __restrict__ Aq, const short* __restrict__ Bq,
             const float* __restrict__ bias, short* __restrict__ h) {
  constexpr int KD = DIM;
  __shared__ short lA[128 * 32];
  __shared__ short lB[128 * 32];
  const int tid = threadIdx.x;
  const int n0 = blockIdx.x * 128, m0 = blockIdx.y * 128;
  const short* gA = Aq + (size_t)(m0 + (tid >> 2)) * KD + (tid & 3) * 8;
  const short* gB = Bq + (size_t)(n0 + (tid >> 2)) * KD + (tid & 3) * 8;
  char* la = (char*)lA + tid * 16;
  char* lbp = (char*)lB + tid * 16;
  f32x4 acc[4][4] = {};
  const int lane = tid & 63, wid = tid >> 6;
  const int wm = (wid >> 1) * 64, wn = (wid & 1) * 64;
  const int lr = lane & 15, kb = (lane >> 4) * 8;
  for (int kt = 0; kt < KD / 32; ++kt) {
    async16(la, gA + kt * 32);
    async16(la + 4096, gA + 64 * KD + kt * 32);
    async16(lbp, gB + kt * 32);
    async16(lbp + 4096, gB + 64 * KD + kt * 32);
    __syncthreads();
    s16x8 af[4], bfr[4];
    #pragma unroll
    for (int i = 0; i < 4; ++i) af[i] = *(const s16x8*)(lA + (wm + i * 16 + lr) * 32 + kb);
    #pragma unroll
    for (int i = 0; i < 4; ++i) bfr[i] = *(const s16x8*)(lB + (wn + i * 16 + lr) * 32 + kb);
    #pragma unroll
    for (int i = 0; i < 4; ++i)
      #pragma unroll
      for (int j = 0; j < 4; ++j)
        acc[i][j] = __builtin_amdgcn_mfma_f32_16x16x32_bf16(af[i], bfr[j], acc[i][j], 0, 0, 0);
    __syncthreads();
  }
  #pragma unroll
  for (int i = 0; i < 4; ++i) {
    const int tok0 = m0 + wm + i * 16 + ((lane >> 4) << 2);
    #pragma unroll
    for (int j = 0; j < 4; ++j) {
      const int f = n0 + wn + j * 16 + lr;
      const float bb = bias[f];
      #pragma unroll
      for (int r = 0; r < 4; ++r) {
        float hv = acc[i][j][r] + bb;
        hv = 0.5f * hv * (1.0f + erff(hv * 0.70710678118654752f));
        h[(size_t)(tok0 + r) * INTER + f] = f2bf(hv);
      }
    }
  }
}

// ---------------- per-row act-quant of h (in place) -------------------------
__global__ __launch_bounds__(192)
void rowquant_k(short* __restrict__ h) {
  __shared__ float wmx[3];
  const int row = blockIdx.x, tid = threadIdx.x;
  short* hr = h + (size_t)row * INTER;
  s16x8 v = *(const s16x8*)(hr + tid * 8);
  float f[8];
  float m = 0.f;
  #pragma unroll
  for (int j = 0; j < 8; ++j) { f[j] = bf2f(v[j]); m = fmaxf(m, fabsf(f[j])); }
  #pragma unroll
  for (int off = 32; off; off >>= 1) m = fmaxf(m, __shfl_xor(m, off));
  if ((tid & 63) == 0) wmx[tid >> 6] = m;
  __syncthreads();
  m = fmaxf(fmaxf(wmx[0], wmx[1]), wmx[2]);
  float mm = fmaxf(m, 1e-5f);
  float ss = 127.f / mm, si = mm * (1.f / 127.f);
  s16x8 o;
  #pragma unroll
  for (int j = 0; j < 8; ++j) {
    float q = fminf(fmaxf(rintf(f[j] * ss), -128.f), 127.f) * si;
    o[j] = f2bf(q);
  }
  *(s16x8*)(hr + tid * 8) = o;
}

// ---------------- GEMM2: out[b,c,t] = x + gamma[c]*(hq[t][:]·wq2[c][:]+b2) --
__global__ __launch_bounds__(256)
void gemm2_k(const short* __restrict__ Aq /*wq2*/, const short* __restrict__ Bq /*hq*/,
             const float* __restrict__ b2, const float* __restrict__ gamma,
             const float* __restrict__ x, float* __restrict__ out) {
  constexpr int KD = INTER;
  __shared__ short lA[128 * 32];
  __shared__ short lB[128 * 32];
  const int tid = threadIdx.x;
  const int m0 = blockIdx.x * 128;   // channel tiles (4)
  const int n0 = blockIdx.y * 128;   // token tiles (256)
  const short* gA = Aq + (size_t)(m0 + (tid >> 2)) * KD + (tid & 3) * 8;
  const short* gB = Bq + (size_t)(n0 + (tid >> 2)) * KD + (tid & 3) * 8;
  char* la = (char*)lA + tid * 16;
  char* lbp = (char*)lB + tid * 16;
  f32x4 acc[4][4] = {};
  const int lane = tid & 63, wid = tid >> 6;
  const int wm = (wid >> 1) * 64, wn = (wid & 1) * 64;
  const int lr = lane & 15, kb = (lane >> 4) * 8;
  for (int kt = 0; kt < KD / 32; ++kt) {
    async16(la, gA + kt * 32);
    async16(la + 4096, gA + 64 * KD + kt * 32);
    async16(lbp, gB + kt * 32);
    async16(lbp + 4096, gB + 64 * KD + kt * 32);
    __syncthreads();
    s16x8 af[4], bfr[4];
    #pragma unroll
    for (int i = 0; i < 4; ++i) af[i] = *(const s16x8*)(lA + (wm + i * 16 + lr) * 32 + kb);
    #pragma unroll
    for (int i = 0; i < 4; ++i) bfr[i] = *(const s16x8*)(lB + (wn + i * 16 + lr) * 32 + kb);
    #pragma unroll
    for (int i = 0; i < 4; ++i)
      #pragma unroll
      for (int j = 0; j < 4; ++j)
        acc[i][j] = __builtin_amdgcn_mfma_f32_16x16x32_bf16(af[i], bfr[j], acc[i][j], 0, 0, 0);
    __syncthreads();
  }
  #pragma unroll
  for (int i = 0; i < 4; ++i) {
    const int c0 = m0 + wm + i * 16 + ((lane >> 4) << 2);
    #pragma unroll
    for (int j = 0; j < 4; ++j) {
      const int tok = n0 + wn + j * 16 + lr;
      const int bb = tok >> 12;
      const int tt = tok & 4095;
      #pragma unroll
      for (int r = 0; r < 4; ++r) {
        const int c = c0 + r;
        float o = acc[i][j][r] + b2[c];
        size_t idx = ((size_t)(bb * DIM + c)) * TLEN + tt;
        out[idx] = x[idx] + gamma[c] * o;
      }
    }
  }
}

// ---------------------------------------------------------------------------
extern "C" void kernel_launch(void* const* d_in, const int* in_sizes, int n_in,
                              void* d_out, int out_size, void* d_ws, size_t ws_size,
                              hipStream_t stream) {
  const float* x    = (const float*)d_in[0];
  const float* dww  = (const float*)d_in[1];
  const float* dwb  = (const float*)d_in[2];
  const float* lng  = (const float*)d_in[3];
  const float* lnb  = (const float*)d_in[4];
  const float* w1   = (const float*)d_in[5];
  const float* b1   = (const float*)d_in[6];
  const float* w2   = (const float*)d_in[7];
  const float* b2   = (const float*)d_in[8];
  const float* gam  = (const float*)d_in[9];
  float* out = (float*)d_out;

  const size_t NEEDED = 137498624;
  if (ws_size < NEEDED) return;

  char* ws = (char*)d_ws;
  float* scales = (float*)ws;
  float* amax   = (float*)(ws + 4096);
  short* wq1    = (short*)(ws + 135168);
  short* wq2    = (short*)(ws + 1708032);
  short* yq     = (short*)(ws + 3280896);
  short* h      = (short*)(ws + 36835328);

  reduce_abs_k<<<128, 256, 0, stream>>>(w1, INTER * DIM, scales + 16);
  reduce_abs_k<<<128, 256, 0, stream>>>(w2, INTER * DIM, scales + 144);
  reduce_abs_k<<<8, 256, 0, stream>>>(dww, DIM * 7, scales + 272);
  finalize_scales_k<<<1, 64, 0, stream>>>(scales);
  quant_w_k<<<3072, 256, 0, stream>>>(w1, INTER * DIM, scales + 0, wq1);
  quant_w_k<<<3072, 256, 0, stream>>>(w2, INTER * DIM, scales + 1, wq2);
  amax_k<<<dim3(TLEN / 128, BATCH), 256, 0, stream>>>(x, amax);
  conv_ln_quant_k<<<dim3(TLEN / 64, BATCH), 256, 0, stream>>>(x, dww, dwb, lng, lnb,
                                                              amax, scales, yq);
  gemm1_k<<<dim3(INTER / 128, NTOK / 128), 256, 0, stream>>>(yq, wq1, b1, h);
  rowquant_k<<<NTOK, 192, 0, stream>>>(h);
  gemm2_k<<<dim3(DIM / 128, NTOK / 128), 256, 0, stream>>>(wq2, h, b2, gam, x, out);
}

// Round 3
// 331.791 us; speedup vs baseline: 1.2895x; 1.1007x over previous
//
#include <hip/hip_runtime.h>
#include <hip/hip_bf16.h>

#define BATCH 8
#define DIM   512
#define TLEN  4096
#define INTER 1536
#define NTOK  (BATCH*TLEN)

typedef __attribute__((ext_vector_type(4))) float f32x4;
typedef __attribute__((ext_vector_type(8))) short s16x8;
typedef __attribute__((ext_vector_type(4))) int   i32x4;
typedef signed char i8;

__device__ __forceinline__ float bf2f(short s) {
  unsigned u = ((unsigned)(unsigned short)s) << 16;
  return __uint_as_float(u);
}
__device__ __forceinline__ short f2bf(float f) {
  union { __hip_bfloat16 h; unsigned short u; } cv;
  cv.h = __float2bfloat16(f);
  return (short)cv.u;
}
__device__ __forceinline__ void async16(void* lds, const void* g) {
  __builtin_amdgcn_global_load_lds((const __attribute__((address_space(1))) void*)g,
                                   (__attribute__((address_space(3))) void*)lds, 16, 0, 0);
}
__device__ __forceinline__ float gelu_tanh(float h) {
  // tanh-approx GELU; branch is scaled by gamma=1e-6 so approx error is negligible
  float u = h * h;
  float z = h * (0.7978845608f + 0.0356774081f * u);
  float e = __expf(-2.f * z);
  float th = (1.f - e) / (1.f + e);
  return 0.5f * h * (1.f + th);
}

// ---------------- weight-scale reduction (two-stage, deterministic) ----------
__global__ __launch_bounds__(256)
void reduce_abs_k(const float* __restrict__ w, int n, float* __restrict__ partial) {
  int tid = threadIdx.x;
  float s = 0.f;
  for (int i = blockIdx.x * 256 + tid; i < n; i += gridDim.x * 256) s += fabsf(w[i]);
  #pragma unroll
  for (int off = 32; off; off >>= 1) s += __shfl_xor(s, off);
  __shared__ float ls[4];
  if ((tid & 63) == 0) ls[tid >> 6] = s;
  __syncthreads();
  if (tid == 0) partial[blockIdx.x] = ls[0] + ls[1] + ls[2] + ls[3];
}

__global__ void finalize_scales_k(float* __restrict__ ws) {
  if (threadIdx.x == 0) {
    float s = 0.f;
    for (int i = 0; i < 128; ++i) s += ws[16 + i];
    ws[0] = fmaxf(s / 786432.f, 1e-5f);          // sw1
    s = 0.f;
    for (int i = 0; i < 128; ++i) s += ws[144 + i];
    ws[1] = fmaxf(s / 786432.f, 1e-5f);          // sw2
    s = 0.f;
    for (int i = 0; i < 8; ++i) s += ws[272 + i];
    ws[2] = fmaxf(s / 3584.f, 1e-5f);            // sdw
  }
}

__global__ __launch_bounds__(256)
void quant_w8_k(const float* __restrict__ w, int n, const float* __restrict__ sp,
                i8* __restrict__ o) {
  int i = blockIdx.x * 256 + threadIdx.x;
  if (i < n) {
    float s = sp[0];
    o[i] = (i8)(int)fminf(fmaxf(rintf(w[i] / s), -1.f), 1.f);
  }
}

// ---------------- per-token absmax of x over DIM ----------------------------
__global__ __launch_bounds__(256)
void amax_k(const float* __restrict__ x, float* __restrict__ amax) {
  int tid = threadIdx.x;
  int b = blockIdx.y;
  int t0 = blockIdx.x * 128;
  int tk = tid & 127, half = tid >> 7;
  const float* xb = x + ((size_t)b * DIM + half * 256) * TLEN + t0 + tk;
  float m = 0.f;
  for (int c = 0; c < 256; ++c) m = fmaxf(m, fabsf(xb[(size_t)c * TLEN]));
  __shared__ float pm[256];
  pm[tid] = m;
  __syncthreads();
  if (tid < 128) amax[(size_t)b * TLEN + t0 + tid] = fmaxf(pm[tid], pm[tid + 128]);
}

// ---------------- fused: act-quant -> depthwise conv -> LN -> act-quant(i8) -
__global__ __launch_bounds__(256)
void conv_ln_quant_k(const float* __restrict__ x, const float* __restrict__ dww,
                     const float* __restrict__ dwb, const float* __restrict__ lng,
                     const float* __restrict__ lnb, const float* __restrict__ amax,
                     const float* __restrict__ scales, i8* __restrict__ yq,
                     float* __restrict__ siy) {
  __shared__ short ly[64 * 512];          // [t][c] bf16, row = 1024 B
  __shared__ float sx[72], sxi[72];
  const int tid = threadIdx.x;
  const int b = blockIdx.y;
  const int t0 = blockIdx.x * 64;

  if (tid < 72) {
    int tg = t0 - 4 + tid;
    float a = (tg >= 0 && tg < TLEN) ? amax[(size_t)b * TLEN + tg] : 1.f;
    float m = fmaxf(a, 1e-5f);
    sx[tid] = 127.f / m;
    sxi[tid] = m * (1.f / 127.f);
  }
  __syncthreads();

  const float sdw = scales[2];
  const float rs = 1.f / sdw;
  const int c0 = tid * 2;
  float w0[7], w1[7];
  #pragma unroll
  for (int k = 0; k < 7; ++k) {
    w0[k] = fminf(fmaxf(rintf(dww[c0 * 7 + k] * rs), -1.f), 1.f) * sdw;
    w1[k] = fminf(fmaxf(rintf(dww[c0 * 7 + 7 + k] * rs), -1.f), 1.f) * sdw;
  }
  const float bias0 = dwb[c0], bias1 = dwb[c0 + 1];
  const float* xr0 = x + ((size_t)b * DIM + c0) * TLEN + t0;
  const float* xr1 = xr0 + TLEN;
  const bool interior = (t0 >= 4) && (t0 + 68 <= TLEN);

  #define LOADQ(xr, u, Q) do {                                            \
    f32x4 L_;                                                             \
    if (interior) L_ = *(const f32x4*)((xr) - 4 + 4 * (u));               \
    else {                                                                \
      _Pragma("unroll")                                                   \
      for (int e_ = 0; e_ < 4; ++e_) {                                    \
        int tg_ = t0 - 4 + 4 * (u) + e_;                                  \
        L_[e_] = (tg_ >= 0 && tg_ < TLEN) ? (xr)[-4 + 4 * (u) + e_] : 0.f;\
      }                                                                   \
    }                                                                     \
    _Pragma("unroll")                                                     \
    for (int e_ = 0; e_ < 4; ++e_) {                                      \
      int j_ = 4 * (u) + e_;                                              \
      Q[e_] = fminf(fmaxf(rintf(L_[e_] * sx[j_]), -128.f), 127.f) * sxi[j_]; \
    }                                                                     \
  } while (0)

  f32x4 A0, A1, A2, B0, B1, B2;
  LOADQ(xr0, 0, A0); LOADQ(xr0, 1, A1);
  LOADQ(xr1, 0, B0); LOADQ(xr1, 1, B1);
  #pragma unroll 4
  for (int u = 0; u < 16; ++u) {
    LOADQ(xr0, u + 2, A2);
    LOADQ(xr1, u + 2, B2);
    #pragma unroll
    for (int s = 0; s < 4; ++s) {
      float a0 = bias0, a1 = bias1;
      #pragma unroll
      for (int k = 0; k < 7; ++k) {
        const int i = s + 1 + k;
        const float qa = (i < 4) ? A0[i & 3] : (i < 8) ? A1[i & 3] : A2[i & 3];
        const float qb = (i < 4) ? B0[i & 3] : (i < 8) ? B1[i & 3] : B2[i & 3];
        a0 += w0[k] * qa;
        a1 += w1[k] * qb;
      }
      const int t = 4 * u + s;
      unsigned pk = (unsigned)(unsigned short)f2bf(a0) |
                    ((unsigned)(unsigned short)f2bf(a1) << 16);
      *(unsigned*)((char*)ly + t * 1024 + tid * 4) = pk;
    }
    A0 = A1; A1 = A2; B0 = B1; B1 = B2;
  }
  #undef LOADQ
  __syncthreads();

  // LN + int8 act-quant
  const int lane = tid & 63, w = tid >> 6;
  float gg[8], bb[8];
  #pragma unroll
  for (int j = 0; j < 8; ++j) { gg[j] = lng[lane * 8 + j]; bb[j] = lnb[lane * 8 + j]; }
  for (int i = 0; i < 16; ++i) {
    const int t = w * 16 + i;
    s16x8 v = *(const s16x8*)((char*)ly + t * 1024 + lane * 16);
    float f[8];
    float s = 0.f, sq = 0.f;
    #pragma unroll
    for (int j = 0; j < 8; ++j) { f[j] = bf2f(v[j]); s += f[j]; sq += f[j] * f[j]; }
    #pragma unroll
    for (int off = 32; off; off >>= 1) { s += __shfl_xor(s, off); sq += __shfl_xor(sq, off); }
    const float mu = s * (1.f / 512.f);
    const float var = sq * (1.f / 512.f) - mu * mu;
    const float rstd = rsqrtf(var + 1e-6f);
    float amx = 0.f;
    #pragma unroll
    for (int j = 0; j < 8; ++j) {
      f[j] = (f[j] - mu) * rstd * gg[j] + bb[j];
      amx = fmaxf(amx, fabsf(f[j]));
    }
    #pragma unroll
    for (int off = 32; off; off >>= 1) amx = fmaxf(amx, __shfl_xor(amx, off));
    const float m = fmaxf(amx, 1e-5f);
    const float ss = 127.f / m;
    const size_t tok = (size_t)(b * TLEN + t0 + t);
    if (lane == 0) siy[tok] = m * (1.f / 127.f);
    unsigned lo = 0, hi = 0;
    #pragma unroll
    for (int j = 0; j < 4; ++j) {
      int q = (int)fminf(fmaxf(rintf(f[j] * ss), -128.f), 127.f);
      lo |= ((unsigned)(q & 255)) << (8 * j);
    }
    #pragma unroll
    for (int j = 4; j < 8; ++j) {
      int q = (int)fminf(fmaxf(rintf(f[j] * ss), -128.f), 127.f);
      hi |= ((unsigned)(q & 255)) << (8 * (j - 4));
    }
    uint2 pk; pk.x = lo; pk.y = hi;
    *(uint2*)(yq + tok * DIM + lane * 8) = pk;
  }
}

// ---------------- GEMM1 fused: 32 tokens x full INTER, gelu+rowquant+i8 out -
// A tile [32][512] i8 in LDS (XOR-swizzled); B (w1q) streamed from L2 to regs.
__global__ __launch_bounds__(512)
void gemm1_fused_k(const i8* __restrict__ yq, const i8* __restrict__ w1q,
                   const float* __restrict__ b1, const float* __restrict__ siy,
                   const float* __restrict__ scales,
                   i8* __restrict__ hq, float* __restrict__ sih) {
  __shared__ i8 lA[32 * 512];        // 16 KB
  __shared__ float pmax[32][8];
  __shared__ float sfin[32];
  const int tid = threadIdx.x;
  const int t0 = blockIdx.x * 32;

  {  // stage A: linear LDS dest, inverse-swizzled global source (G21)
    const int row = tid >> 5;        // 0..15
    const int cf = tid & 31;
    async16((char*)lA + tid * 16,
            yq + (size_t)(t0 + row) * 512 + (size_t)(cf ^ (row & 7)) * 16);
    const int row1 = row + 16;
    async16((char*)lA + 8192 + tid * 16,
            yq + (size_t)(t0 + row1) * 512 + (size_t)(cf ^ (row1 & 7)) * 16);
  }

  const int lane = tid & 63, wid = tid >> 6;
  const int wcol = wid * 192;
  const int lc = lane & 15, lg = lane >> 4;
  i32x4 acc[2][12] = {};
  __syncthreads();

  #pragma unroll 2
  for (int kt = 0; kt < 8; ++kt) {
    i32x4 af[2];
    #pragma unroll
    for (int rf = 0; rf < 2; ++rf) {
      int r = rf * 16 + lc;
      int ch = (kt * 4 + lg) ^ (r & 7);
      af[rf] = *(const i32x4*)((const char*)lA + r * 512 + ch * 16);
    }
    #pragma unroll
    for (int j = 0; j < 12; ++j) {
      i32x4 bfr = *(const i32x4*)(w1q + (size_t)(wcol + j * 16 + lc) * 512
                                  + kt * 64 + lg * 16);
      acc[0][j] = __builtin_amdgcn_mfma_i32_16x16x64_i8(af[0], bfr, acc[0][j], 0, 0, 0);
      acc[1][j] = __builtin_amdgcn_mfma_i32_16x16x64_i8(af[1], bfr, acc[1][j], 0, 0, 0);
    }
  }

  // epilogue: dequant + bias + gelu, track per-row max
  const float sw1 = scales[0];
  float b1c[12];
  #pragma unroll
  for (int j = 0; j < 12; ++j) b1c[j] = b1[wcol + j * 16 + lc];
  float sy[2][4];
  #pragma unroll
  for (int rf = 0; rf < 2; ++rf)
    #pragma unroll
    for (int r = 0; r < 4; ++r) sy[rf][r] = siy[t0 + rf * 16 + lg * 4 + r] * sw1;

  float g[2][12][4];
  float rmax[2][4];
  #pragma unroll
  for (int rf = 0; rf < 2; ++rf)
    #pragma unroll
    for (int r = 0; r < 4; ++r) {
      float mx = 0.f;
      #pragma unroll
      for (int j = 0; j < 12; ++j) {
        float hv = (float)acc[rf][j][r] * sy[rf][r] + b1c[j];
        float gv = gelu_tanh(hv);
        g[rf][j][r] = gv;
        mx = fmaxf(mx, fabsf(gv));
      }
      rmax[rf][r] = mx;
    }
  // reduce across the 16 column-lanes (bits 0..3 of lane)
  #pragma unroll
  for (int off = 1; off < 16; off <<= 1)
    #pragma unroll
    for (int rf = 0; rf < 2; ++rf)
      #pragma unroll
      for (int r = 0; r < 4; ++r)
        rmax[rf][r] = fmaxf(rmax[rf][r], __shfl_xor(rmax[rf][r], off));
  if (lc == 0) {
    #pragma unroll
    for (int rf = 0; rf < 2; ++rf)
      #pragma unroll
      for (int r = 0; r < 4; ++r)
        pmax[rf * 16 + lg * 4 + r][wid] = rmax[rf][r];
  }
  __syncthreads();
  if (tid < 32) {
    float rm = 0.f;
    #pragma unroll
    for (int w2 = 0; w2 < 8; ++w2) rm = fmaxf(rm, pmax[tid][w2]);
    float m = fmaxf(rm, 1e-5f);
    sfin[tid] = 127.f / m;
    sih[t0 + tid] = m * (1.f / 127.f);
  }
  __syncthreads();
  #pragma unroll
  for (int rf = 0; rf < 2; ++rf)
    #pragma unroll
    for (int r = 0; r < 4; ++r) {
      const int row = rf * 16 + lg * 4 + r;
      const float sc = sfin[row];
      i8* hr = hq + (size_t)(t0 + row) * INTER + wcol + lc;
      #pragma unroll
      for (int j = 0; j < 12; ++j) {
        int q = (int)fminf(fmaxf(rintf(g[rf][j][r] * sc), -128.f), 127.f);
        hr[j * 16] = (i8)q;
      }
    }
}

// ---------------- GEMM2: out[b,c,t] = x + gamma[c]*(i8 GEMM + b2) ----------
__global__ __launch_bounds__(256)
void gemm2_k(const i8* __restrict__ w2q, const i8* __restrict__ hq,
             const float* __restrict__ b2, const float* __restrict__ gamma,
             const float* __restrict__ sih, const float* __restrict__ scales,
             const float* __restrict__ x, float* __restrict__ out) {
  __shared__ i8 lA[128 * 128];   // 16 KB, XOR-swizzled
  __shared__ i8 lB[128 * 128];
  const int tid = threadIdx.x;
  const int m0 = blockIdx.x * 128;   // channels (4 tiles)
  const int n0 = blockIdx.y * 128;   // tokens  (256 tiles)
  const int lane = tid & 63, wid = tid >> 6;
  const int wm = (wid >> 1) * 64, wn = (wid & 1) * 64;
  const int lc = lane & 15, lg = lane >> 4;
  const int srow = tid >> 3;         // staging row within 32-row pass
  const int scf = tid & 7;
  i32x4 acc[4][4] = {};
  for (int kt = 0; kt < 12; ++kt) {
    #pragma unroll
    for (int p = 0; p < 4; ++p) {
      int row = p * 32 + srow;
      int cg = scf ^ (row & 7);
      async16((char*)lA + p * 4096 + tid * 16,
              w2q + (size_t)(m0 + row) * INTER + kt * 128 + cg * 16);
      async16((char*)lB + p * 4096 + tid * 16,
              hq + (size_t)(n0 + row) * INTER + kt * 128 + cg * 16);
    }
    __syncthreads();
    #pragma unroll
    for (int s = 0; s < 2; ++s) {
      i32x4 af[4], bfr[4];
      #pragma unroll
      for (int i = 0; i < 4; ++i) {
        int r = wm + i * 16 + lc;
        int ch = (s * 4 + lg) ^ (r & 7);
        af[i] = *(const i32x4*)((const char*)lA + r * 128 + ch * 16);
      }
      #pragma unroll
      for (int j = 0; j < 4; ++j) {
        int r = wn + j * 16 + lc;
        int ch = (s * 4 + lg) ^ (r & 7);
        bfr[j] = *(const i32x4*)((const char*)lB + r * 128 + ch * 16);
      }
      #pragma unroll
      for (int i = 0; i < 4; ++i)
        #pragma unroll
        for (int j = 0; j < 4; ++j)
          acc[i][j] = __builtin_amdgcn_mfma_i32_16x16x64_i8(af[i], bfr[j], acc[i][j], 0, 0, 0);
    }
    __syncthreads();
  }
  const float sw2 = scales[1];
  #pragma unroll
  for (int i = 0; i < 4; ++i) {
    const int c0 = m0 + wm + i * 16 + lg * 4;
    #pragma unroll
    for (int j = 0; j < 4; ++j) {
      const int tok = n0 + wn + j * 16 + lc;
      const float sdq = sih[tok] * sw2;
      const int bb = tok >> 12;
      const int tt = tok & 4095;
      #pragma unroll
      for (int r = 0; r < 4; ++r) {
        const int c = c0 + r;
        float o = (float)acc[i][j][r] * sdq + b2[c];
        size_t idx = ((size_t)(bb * DIM + c)) * TLEN + tt;
        out[idx] = x[idx] + gamma[c] * o;
      }
    }
  }
}

// ---------------------------------------------------------------------------
extern "C" void kernel_launch(void* const* d_in, const int* in_sizes, int n_in,
                              void* d_out, int out_size, void* d_ws, size_t ws_size,
                              hipStream_t stream) {
  const float* x    = (const float*)d_in[0];
  const float* dww  = (const float*)d_in[1];
  const float* dwb  = (const float*)d_in[2];
  const float* lng  = (const float*)d_in[3];
  const float* lnb  = (const float*)d_in[4];
  const float* w1   = (const float*)d_in[5];
  const float* b1   = (const float*)d_in[6];
  const float* w2   = (const float*)d_in[7];
  const float* b2   = (const float*)d_in[8];
  const float* gam  = (const float*)d_in[9];
  float* out = (float*)d_out;

  // ws layout (bytes):
  //   0        scales+partials   4 KB
  //   4096     amax   [NTOK] f32  128 KB
  //   135168   siy    [NTOK] f32  128 KB
  //   266240   sih    [NTOK] f32  128 KB
  //   397312   w1q    i8 768 KB
  //   1183744  w2q    i8 768 KB
  //   1970176  yq     [NTOK*DIM]   i8 16 MB
  //   18747392 hq     [NTOK*INTER] i8 48 MB   -> total 69079040
  const size_t NEEDED = 69079040;
  if (ws_size < NEEDED) return;

  char* ws = (char*)d_ws;
  float* scales = (float*)ws;
  float* amax   = (float*)(ws + 4096);
  float* siy    = (float*)(ws + 135168);
  float* sih    = (float*)(ws + 266240);
  i8* w1q       = (i8*)(ws + 397312);
  i8* w2q       = (i8*)(ws + 1183744);
  i8* yq        = (i8*)(ws + 1970176);
  i8* hq        = (i8*)(ws + 18747392);

  reduce_abs_k<<<128, 256, 0, stream>>>(w1, INTER * DIM, scales + 16);
  reduce_abs_k<<<128, 256, 0, stream>>>(w2, INTER * DIM, scales + 144);
  reduce_abs_k<<<8, 256, 0, stream>>>(dww, DIM * 7, scales + 272);
  finalize_scales_k<<<1, 64, 0, stream>>>(scales);
  quant_w8_k<<<3072, 256, 0, stream>>>(w1, INTER * DIM, scales + 0, w1q);
  quant_w8_k<<<3072, 256, 0, stream>>>(w2, INTER * DIM, scales + 1, w2q);
  amax_k<<<dim3(TLEN / 128, BATCH), 256, 0, stream>>>(x, amax);
  conv_ln_quant_k<<<dim3(TLEN / 64, BATCH), 256, 0, stream>>>(x, dww, dwb, lng, lnb,
                                                              amax, scales, yq, siy);
  gemm1_fused_k<<<NTOK / 32, 512, 0, stream>>>(yq, w1q, b1, siy, scales, hq, sih);
  gemm2_k<<<dim3(DIM / 128, NTOK / 128), 256, 0, stream>>>(w2q, hq, b2, gam, sih,
                                                           scales, x, out);
}

// Round 4
// 277.122 us; speedup vs baseline: 1.5439x; 1.1973x over previous
//
#include <hip/hip_runtime.h>
#include <hip/hip_bf16.h>

#define BATCH 8
#define DIM   512
#define TLEN  4096
#define INTER 1536
#define NTOK  (BATCH*TLEN)

typedef __attribute__((ext_vector_type(4))) float f32x4;
typedef __attribute__((ext_vector_type(8))) short s16x8;
typedef __attribute__((ext_vector_type(4))) int   i32x4;
typedef signed char i8;

__device__ __forceinline__ float bf2f(short s) {
  unsigned u = ((unsigned)(unsigned short)s) << 16;
  return __uint_as_float(u);
}
__device__ __forceinline__ short f2bf(float f) {
  union { __hip_bfloat16 h; unsigned short u; } cv;
  cv.h = __float2bfloat16(f);
  return (short)cv.u;
}
__device__ __forceinline__ void async16(void* lds, const void* g) {
  __builtin_amdgcn_global_load_lds((const __attribute__((address_space(1))) void*)g,
                                   (__attribute__((address_space(3))) void*)lds, 16, 0, 0);
}
__device__ __forceinline__ float gelu_tanh(float h) {
  // tanh-approx GELU; branch is scaled by gamma=1e-6 so approx error is negligible
  float u = h * h;
  float z = h * (0.7978845608f + 0.0356774081f * u);
  float e = __expf(-2.f * z);
  float th = (1.f - e) / (1.f + e);
  return 0.5f * h * (1.f + th);
}

// ---------------- weight-scale reduction (two-stage, deterministic) ----------
__global__ __launch_bounds__(256)
void reduce_abs_k(const float* __restrict__ w, int n, float* __restrict__ partial) {
  int tid = threadIdx.x;
  float s = 0.f;
  for (int i = blockIdx.x * 256 + tid; i < n; i += gridDim.x * 256) s += fabsf(w[i]);
  #pragma unroll
  for (int off = 32; off; off >>= 1) s += __shfl_xor(s, off);
  __shared__ float ls[4];
  if ((tid & 63) == 0) ls[tid >> 6] = s;
  __syncthreads();
  if (tid == 0) partial[blockIdx.x] = ls[0] + ls[1] + ls[2] + ls[3];
}

__global__ void finalize_scales_k(float* __restrict__ ws) {
  if (threadIdx.x == 0) {
    float s = 0.f;
    for (int i = 0; i < 128; ++i) s += ws[16 + i];
    ws[0] = fmaxf(s / 786432.f, 1e-5f);          // sw1
    s = 0.f;
    for (int i = 0; i < 128; ++i) s += ws[144 + i];
    ws[1] = fmaxf(s / 786432.f, 1e-5f);          // sw2
    s = 0.f;
    for (int i = 0; i < 8; ++i) s += ws[272 + i];
    ws[2] = fmaxf(s / 3584.f, 1e-5f);            // sdw
  }
}

__global__ __launch_bounds__(256)
void quant_w8_k(const float* __restrict__ w, int n, const float* __restrict__ sp,
                i8* __restrict__ o) {
  int i = blockIdx.x * 256 + threadIdx.x;
  if (i < n) {
    float s = sp[0];
    o[i] = (i8)(int)fminf(fmaxf(rintf(w[i] / s), -1.f), 1.f);
  }
}

// ---------------- per-token absmax of x over DIM ----------------------------
__global__ __launch_bounds__(256)
void amax_k(const float* __restrict__ x, float* __restrict__ amax) {
  int tid = threadIdx.x;
  int b = blockIdx.y;
  int t0 = blockIdx.x * 128;
  int tk = tid & 127, half = tid >> 7;
  const float* xb = x + ((size_t)b * DIM + half * 256) * TLEN + t0 + tk;
  float m = 0.f;
  for (int c = 0; c < 256; ++c) m = fmaxf(m, fabsf(xb[(size_t)c * TLEN]));
  __shared__ float pm[256];
  pm[tid] = m;
  __syncthreads();
  if (tid < 128) amax[(size_t)b * TLEN + t0 + tid] = fmaxf(pm[tid], pm[tid + 128]);
}

// ---------------- fused: act-quant -> depthwise conv -> LN -> act-quant(i8) -
__global__ __launch_bounds__(256)
void conv_ln_quant_k(const float* __restrict__ x, const float* __restrict__ dww,
                     const float* __restrict__ dwb, const float* __restrict__ lng,
                     const float* __restrict__ lnb, const float* __restrict__ amax,
                     const float* __restrict__ scales, i8* __restrict__ yq,
                     float* __restrict__ siy) {
  __shared__ short ly[64 * 512];          // [t][c] bf16, row = 1024 B
  __shared__ float sx[72], sxi[72];
  const int tid = threadIdx.x;
  const int b = blockIdx.y;
  const int t0 = blockIdx.x * 64;

  if (tid < 72) {
    int tg = t0 - 4 + tid;
    float a = (tg >= 0 && tg < TLEN) ? amax[(size_t)b * TLEN + tg] : 1.f;
    float m = fmaxf(a, 1e-5f);
    sx[tid] = 127.f / m;
    sxi[tid] = m * (1.f / 127.f);
  }
  __syncthreads();

  const float sdw = scales[2];
  const float rs = 1.f / sdw;
  const int c0 = tid * 2;
  float w0[7], w1[7];
  #pragma unroll
  for (int k = 0; k < 7; ++k) {
    w0[k] = fminf(fmaxf(rintf(dww[c0 * 7 + k] * rs), -1.f), 1.f) * sdw;
    w1[k] = fminf(fmaxf(rintf(dww[c0 * 7 + 7 + k] * rs), -1.f), 1.f) * sdw;
  }
  const float bias0 = dwb[c0], bias1 = dwb[c0 + 1];
  const float* xr0 = x + ((size_t)b * DIM + c0) * TLEN + t0;
  const float* xr1 = xr0 + TLEN;
  const bool interior = (t0 >= 4) && (t0 + 68 <= TLEN);

  #define LOADQ(xr, u, Q) do {                                            \
    f32x4 L_;                                                             \
    if (interior) L_ = *(const f32x4*)((xr) - 4 + 4 * (u));               \
    else {                                                                \
      _Pragma("unroll")                                                   \
      for (int e_ = 0; e_ < 4; ++e_) {                                    \
        int tg_ = t0 - 4 + 4 * (u) + e_;                                  \
        L_[e_] = (tg_ >= 0 && tg_ < TLEN) ? (xr)[-4 + 4 * (u) + e_] : 0.f;\
      }                                                                   \
    }                                                                     \
    _Pragma("unroll")                                                     \
    for (int e_ = 0; e_ < 4; ++e_) {                                      \
      int j_ = 4 * (u) + e_;                                              \
      Q[e_] = fminf(fmaxf(rintf(L_[e_] * sx[j_]), -128.f), 127.f) * sxi[j_]; \
    }                                                                     \
  } while (0)

  f32x4 A0, A1, A2, B0, B1, B2;
  LOADQ(xr0, 0, A0); LOADQ(xr0, 1, A1);
  LOADQ(xr1, 0, B0); LOADQ(xr1, 1, B1);
  #pragma unroll 4
  for (int u = 0; u < 16; ++u) {
    LOADQ(xr0, u + 2, A2);
    LOADQ(xr1, u + 2, B2);
    #pragma unroll
    for (int s = 0; s < 4; ++s) {
      float a0 = bias0, a1 = bias1;
      #pragma unroll
      for (int k = 0; k < 7; ++k) {
        const int i = s + 1 + k;
        const float qa = (i < 4) ? A0[i & 3] : (i < 8) ? A1[i & 3] : A2[i & 3];
        const float qb = (i < 4) ? B0[i & 3] : (i < 8) ? B1[i & 3] : B2[i & 3];
        a0 += w0[k] * qa;
        a1 += w1[k] * qb;
      }
      const int t = 4 * u + s;
      unsigned pk = (unsigned)(unsigned short)f2bf(a0) |
                    ((unsigned)(unsigned short)f2bf(a1) << 16);
      *(unsigned*)((char*)ly + t * 1024 + tid * 4) = pk;
    }
    A0 = A1; A1 = A2; B0 = B1; B1 = B2;
  }
  #undef LOADQ
  __syncthreads();

  // LN + int8 act-quant
  const int lane = tid & 63, w = tid >> 6;
  float gg[8], bb[8];
  #pragma unroll
  for (int j = 0; j < 8; ++j) { gg[j] = lng[lane * 8 + j]; bb[j] = lnb[lane * 8 + j]; }
  for (int i = 0; i < 16; ++i) {
    const int t = w * 16 + i;
    s16x8 v = *(const s16x8*)((char*)ly + t * 1024 + lane * 16);
    float f[8];
    float s = 0.f, sq = 0.f;
    #pragma unroll
    for (int j = 0; j < 8; ++j) { f[j] = bf2f(v[j]); s += f[j]; sq += f[j] * f[j]; }
    #pragma unroll
    for (int off = 32; off; off >>= 1) { s += __shfl_xor(s, off); sq += __shfl_xor(sq, off); }
    const float mu = s * (1.f / 512.f);
    const float var = sq * (1.f / 512.f) - mu * mu;
    const float rstd = rsqrtf(var + 1e-6f);
    float amx = 0.f;
    #pragma unroll
    for (int j = 0; j < 8; ++j) {
      f[j] = (f[j] - mu) * rstd * gg[j] + bb[j];
      amx = fmaxf(amx, fabsf(f[j]));
    }
    #pragma unroll
    for (int off = 32; off; off >>= 1) amx = fmaxf(amx, __shfl_xor(amx, off));
    const float m = fmaxf(amx, 1e-5f);
    const float ss = 127.f / m;
    const size_t tok = (size_t)(b * TLEN + t0 + t);
    if (lane == 0) siy[tok] = m * (1.f / 127.f);
    unsigned lo = 0, hi = 0;
    #pragma unroll
    for (int j = 0; j < 4; ++j) {
      int q = (int)fminf(fmaxf(rintf(f[j] * ss), -128.f), 127.f);
      lo |= ((unsigned)(q & 255)) << (8 * j);
    }
    #pragma unroll
    for (int j = 4; j < 8; ++j) {
      int q = (int)fminf(fmaxf(rintf(f[j] * ss), -128.f), 127.f);
      hi |= ((unsigned)(q & 255)) << (8 * (j - 4));
    }
    uint2 pk; pk.x = lo; pk.y = hi;
    *(uint2*)(yq + tok * DIM + lane * 8) = pk;
  }
}

// ---------------- GEMM1: 128 tok x 128 col tile, fused gelu + tile-quant ----
// D[token][col] = gelu(yq·w1q^T dequant + b1); quant per (token, 128-col tile).
__global__ __launch_bounds__(256)
void gemm1_k(const i8* __restrict__ yq, const i8* __restrict__ w1q,
             const float* __restrict__ b1, const float* __restrict__ siy,
             const float* __restrict__ scales,
             i8* __restrict__ hq, float* __restrict__ siht) {
  __shared__ i8 lA[128 * 128];   // yq token rows, XOR-swizzled
  __shared__ i8 lB[128 * 128];   // w1q col rows
  __shared__ float pmax[128][2];
  __shared__ float sfin[128];
  const int tid = threadIdx.x;
  const int n0 = blockIdx.x * 128;   // col tile (12)
  const int t0 = blockIdx.y * 128;   // token tile (256)
  const int lane = tid & 63, wid = tid >> 6;
  const int wm = (wid >> 1) * 64, wn = (wid & 1) * 64;
  const int lc = lane & 15, lg = lane >> 4;
  const int srow = tid >> 3, scf = tid & 7;
  i32x4 acc[4][4] = {};
  for (int kt = 0; kt < 4; ++kt) {
    #pragma unroll
    for (int p = 0; p < 4; ++p) {
      int row = p * 32 + srow;
      int cg = scf ^ (row & 7);
      async16((char*)lA + p * 4096 + tid * 16,
              yq + (size_t)(t0 + row) * DIM + kt * 128 + cg * 16);
      async16((char*)lB + p * 4096 + tid * 16,
              w1q + (size_t)(n0 + row) * DIM + kt * 128 + cg * 16);
    }
    __syncthreads();
    #pragma unroll
    for (int s = 0; s < 2; ++s) {
      i32x4 af[4], bfr[4];
      #pragma unroll
      for (int i = 0; i < 4; ++i) {
        int r = wm + i * 16 + lc;
        int ch = (s * 4 + lg) ^ (r & 7);
        af[i] = *(const i32x4*)((const char*)lA + r * 128 + ch * 16);
      }
      #pragma unroll
      for (int j = 0; j < 4; ++j) {
        int r = wn + j * 16 + lc;
        int ch = (s * 4 + lg) ^ (r & 7);
        bfr[j] = *(const i32x4*)((const char*)lB + r * 128 + ch * 16);
      }
      #pragma unroll
      for (int i = 0; i < 4; ++i)
        #pragma unroll
        for (int j = 0; j < 4; ++j)
          acc[i][j] = __builtin_amdgcn_mfma_i32_16x16x64_i8(af[i], bfr[j], acc[i][j], 0, 0, 0);
    }
    __syncthreads();
  }
  // epilogue: dequant + bias + gelu; per-token max over this block's 128 cols
  const float sw1 = scales[0];
  float sy[4][4];
  #pragma unroll
  for (int i = 0; i < 4; ++i)
    #pragma unroll
    for (int r = 0; r < 4; ++r)
      sy[i][r] = siy[t0 + wm + i * 16 + lg * 4 + r] * sw1;
  float bcol[4];
  #pragma unroll
  for (int j = 0; j < 4; ++j) bcol[j] = b1[n0 + wn + j * 16 + lc];
  float g[4][4][4];
  float rmax[4][4];
  #pragma unroll
  for (int i = 0; i < 4; ++i)
    #pragma unroll
    for (int r = 0; r < 4; ++r) {
      float mx = 0.f;
      #pragma unroll
      for (int j = 0; j < 4; ++j) {
        float gv = gelu_tanh((float)acc[i][j][r] * sy[i][r] + bcol[j]);
        g[i][j][r] = gv;
        mx = fmaxf(mx, fabsf(gv));
      }
      rmax[i][r] = mx;
    }
  #pragma unroll
  for (int off = 1; off < 16; off <<= 1)
    #pragma unroll
    for (int i = 0; i < 4; ++i)
      #pragma unroll
      for (int r = 0; r < 4; ++r)
        rmax[i][r] = fmaxf(rmax[i][r], __shfl_xor(rmax[i][r], off));
  if (lc == 0) {
    #pragma unroll
    for (int i = 0; i < 4; ++i)
      #pragma unroll
      for (int r = 0; r < 4; ++r)
        pmax[wm + i * 16 + lg * 4 + r][wid & 1] = rmax[i][r];
  }
  __syncthreads();
  if (tid < 128) {
    float m = fmaxf(fmaxf(pmax[tid][0], pmax[tid][1]), 1e-5f);
    sfin[tid] = 127.f / m;
    siht[(size_t)(t0 + tid) * 12 + blockIdx.x] = m * (1.f / 127.f);
  }
  __syncthreads();
  #pragma unroll
  for (int i = 0; i < 4; ++i)
    #pragma unroll
    for (int r = 0; r < 4; ++r) {
      const int row = wm + i * 16 + lg * 4 + r;
      const float sc = sfin[row];
      i8* hr = hq + (size_t)(t0 + row) * INTER + n0 + wn + lc;
      #pragma unroll
      for (int j = 0; j < 4; ++j) {
        int q = (int)fminf(fmaxf(rintf(g[i][j][r] * sc), -128.f), 127.f);
        hr[j * 16] = (i8)q;
      }
    }
}

// ---------------- GEMM2: out[b,c,t] = x + gamma[c]*(Σ_kt i8GEMM*s_kt + b2) --
__global__ __launch_bounds__(256)
void gemm2_k(const i8* __restrict__ w2q, const i8* __restrict__ hq,
             const float* __restrict__ b2, const float* __restrict__ gamma,
             const float* __restrict__ siht, const float* __restrict__ scales,
             const float* __restrict__ x, float* __restrict__ out) {
  __shared__ i8 lA[128 * 128];   // w2q channel rows
  __shared__ i8 lB[128 * 128];   // hq token rows
  const int tid = threadIdx.x;
  const int m0 = blockIdx.x * 128;   // channels (4 tiles)
  const int n0 = blockIdx.y * 128;   // tokens  (256 tiles)
  const int lane = tid & 63, wid = tid >> 6;
  const int wm = (wid >> 1) * 64, wn = (wid & 1) * 64;
  const int lc = lane & 15, lg = lane >> 4;
  const int srow = tid >> 3, scf = tid & 7;
  const float sw2 = scales[1];
  f32x4 facc[4][4] = {};
  for (int kt = 0; kt < 12; ++kt) {
    #pragma unroll
    for (int p = 0; p < 4; ++p) {
      int row = p * 32 + srow;
      int cg = scf ^ (row & 7);
      async16((char*)lA + p * 4096 + tid * 16,
              w2q + (size_t)(m0 + row) * INTER + kt * 128 + cg * 16);
      async16((char*)lB + p * 4096 + tid * 16,
              hq + (size_t)(n0 + row) * INTER + kt * 128 + cg * 16);
    }
    __syncthreads();
    i32x4 acc[4][4] = {};
    #pragma unroll
    for (int s = 0; s < 2; ++s) {
      i32x4 af[4], bfr[4];
      #pragma unroll
      for (int i = 0; i < 4; ++i) {
        int r = wm + i * 16 + lc;
        int ch = (s * 4 + lg) ^ (r & 7);
        af[i] = *(const i32x4*)((const char*)lA + r * 128 + ch * 16);
      }
      #pragma unroll
      for (int j = 0; j < 4; ++j) {
        int r = wn + j * 16 + lc;
        int ch = (s * 4 + lg) ^ (r & 7);
        bfr[j] = *(const i32x4*)((const char*)lB + r * 128 + ch * 16);
      }
      #pragma unroll
      for (int i = 0; i < 4; ++i)
        #pragma unroll
        for (int j = 0; j < 4; ++j)
          acc[i][j] = __builtin_amdgcn_mfma_i32_16x16x64_i8(af[i], bfr[j], acc[i][j], 0, 0, 0);
    }
    __syncthreads();
    // fold int accumulator with per-(token, kt) scale
    #pragma unroll
    for (int j = 0; j < 4; ++j) {
      const int tok = n0 + wn + j * 16 + lc;
      const float sj = siht[(size_t)tok * 12 + kt] * sw2;
      #pragma unroll
      for (int i = 0; i < 4; ++i)
        #pragma unroll
        for (int r = 0; r < 4; ++r)
          facc[i][j][r] += (float)acc[i][j][r] * sj;
    }
  }
  #pragma unroll
  for (int i = 0; i < 4; ++i) {
    const int c0 = m0 + wm + i * 16 + lg * 4;
    #pragma unroll
    for (int j = 0; j < 4; ++j) {
      const int tok = n0 + wn + j * 16 + lc;
      const int bb = tok >> 12;
      const int tt = tok & 4095;
      #pragma unroll
      for (int r = 0; r < 4; ++r) {
        const int c = c0 + r;
        float o = facc[i][j][r] + b2[c];
        size_t idx = ((size_t)(bb * DIM + c)) * TLEN + tt;
        out[idx] = x[idx] + gamma[c] * o;
      }
    }
  }
}

// ---------------------------------------------------------------------------
extern "C" void kernel_launch(void* const* d_in, const int* in_sizes, int n_in,
                              void* d_out, int out_size, void* d_ws, size_t ws_size,
                              hipStream_t stream) {
  const float* x    = (const float*)d_in[0];
  const float* dww  = (const float*)d_in[1];
  const float* dwb  = (const float*)d_in[2];
  const float* lng  = (const float*)d_in[3];
  const float* lnb  = (const float*)d_in[4];
  const float* w1   = (const float*)d_in[5];
  const float* b1   = (const float*)d_in[6];
  const float* w2   = (const float*)d_in[7];
  const float* b2   = (const float*)d_in[8];
  const float* gam  = (const float*)d_in[9];
  float* out = (float*)d_out;

  // ws layout (bytes):
  //   0        scales+partials     4 KB
  //   4096     amax  [NTOK] f32    128 KB
  //   135168   siy   [NTOK] f32    128 KB
  //   266240   siht  [NTOK*12] f32 1.5 MB
  //   1839104  w1q   i8            768 KB
  //   2625536  w2q   i8            768 KB
  //   3411968  yq    [NTOK*DIM]   i8 16 MB
  //   20189184 hq    [NTOK*INTER] i8 48 MB  -> total 70852608
  const size_t NEEDED = 70852608;
  if (ws_size < NEEDED) return;

  char* ws = (char*)d_ws;
  float* scales = (float*)ws;
  float* amax   = (float*)(ws + 4096);
  float* siy    = (float*)(ws + 135168);
  float* siht   = (float*)(ws + 266240);
  i8* w1q       = (i8*)(ws + 1839104);
  i8* w2q       = (i8*)(ws + 2625536);
  i8* yq        = (i8*)(ws + 3411968);
  i8* hq        = (i8*)(ws + 20189184);

  reduce_abs_k<<<128, 256, 0, stream>>>(w1, INTER * DIM, scales + 16);
  reduce_abs_k<<<128, 256, 0, stream>>>(w2, INTER * DIM, scales + 144);
  reduce_abs_k<<<8, 256, 0, stream>>>(dww, DIM * 7, scales + 272);
  finalize_scales_k<<<1, 64, 0, stream>>>(scales);
  quant_w8_k<<<3072, 256, 0, stream>>>(w1, INTER * DIM, scales + 0, w1q);
  quant_w8_k<<<3072, 256, 0, stream>>>(w2, INTER * DIM, scales + 1, w2q);
  amax_k<<<dim3(TLEN / 128, BATCH), 256, 0, stream>>>(x, amax);
  conv_ln_quant_k<<<dim3(TLEN / 64, BATCH), 256, 0, stream>>>(x, dww, dwb, lng, lnb,
                                                              amax, scales, yq, siy);
  gemm1_k<<<dim3(INTER / 128, NTOK / 128), 256, 0, stream>>>(yq, w1q, b1, siy,
                                                             scales, hq, siht);
  gemm2_k<<<dim3(DIM / 128, NTOK / 128), 256, 0, stream>>>(w2q, hq, b2, gam, siht,
                                                           scales, x, out);
}